// Round 7
// baseline (314.350 us; speedup 1.0000x reference)
//
#include <hip/hip_runtime.h>
#include <math.h>

// NoisyTopkRouter: B=8,T=4096,NE=1024,E=16,TOPK=2,LIN=1824
// out = [router 32768*16][indices 32768*2][gate1 32768*16] all f32
//
// R11: DRAM row-locality via block-level split-K. Evidence: R4/R9/R10
// (reg-staged/DMA-drain0/DMA-counted-vmcnt-ring3) ALL serve memory at
// ~2.5 TB/s and land at ~115us; every latency/pipeline theory nulled.
// Surviving theory: 256B-per-4KB-row touch grain, row revisited 28x at
// ~4us spacing -> row-activate-bound HBM (~1 TB/s observed).
// Fix: grid = 256 token-regions x 4 k-groups, KG-MINOR order -> the 512
// co-resident blocks (2/CU) = 128 regions with ALL 4 kgs in flight; kg
// takes chunks {kg+4j}, so synchronized j reads a CONTIGUOUS 1KB window
// of every token row. Partials (128x32) -> d_ws (16.8MB); kernel2 sums
// 4 partials + city/bias + proven epilogue.
// Per block: 7 chunks, R9/R10-proven machinery: A ring-2 DMA (linear LDS
// dest, XOR-pre-swizzled global source, same-XOR read); W reg-staged into
// a SINGLE LDS buffer (fits 2 blocks/CU: 72KB+384 < 80KB). Per-chunk
// sequence: [stage A(j+1),Wglb(j+1)] compute(j) [vmcnt(0) bar sWwrite bar]
// -- the vmcnt-wait has a full compute phase of slack.

#define NCHUNK 7
#define I_OFF 524288        // 32768*16
#define G_OFF 589824        // 524288 + 32768*2
#define SS 36               // score-row stride (16B-aligned: 36*4=144)

__device__ __forceinline__ float softplus_f(float x) {
  return fmaxf(x, 0.0f) + log1pf(expf(-fabsf(x)));
}

__device__ __forceinline__ float get_comp(const float4& v, int kk) {
  return kk == 0 ? v.x : kk == 1 ? v.y : kk == 2 ? v.z : v.w;
}

__device__ __forceinline__ void dma16(const float* g, float* l) {
  __builtin_amdgcn_global_load_lds(
      (const __attribute__((address_space(1))) void*)g,
      (__attribute__((address_space(3))) void*)l, 16, 0, 0);
}

// ---------------- kernel 1: partial GEMM, split-K over blocks ----------------
__global__ __launch_bounds__(512, 2) void router_gemm(
    const float* __restrict__ mh, const float* __restrict__ dt,
    const float* __restrict__ dd, const float* __restrict__ rg,
    const float* __restrict__ de, const float* __restrict__ w_route,
    const float* __restrict__ w_noise, float* __restrict__ ws) {
  // A ring-2: [0,8192) and [8192,16384) | W single: [16384,18432)
  // post-loop overlay in dead A0: sS [128][36] = [0,4608)
  __shared__ float smem[18432];   // 73728 B (+384) -> 2 blocks/CU
  float* sW = smem + 16384;
  float* sS = smem;

  const int tid = threadIdx.x;
  const int w   = tid >> 6;        // wave 0..7: k-slab [w*8, w*8+8) of chunk
  const int ln  = tid & 63;
  const int tg  = ln & 15;         // tokens {tg + 16j}, j=0..7
  const int eg  = ln >> 4;         // e-cols eg*8..+7 (of 32 = route|noise)
  const int tr  = blockIdx.x >> 2; // token region (128 tokens)
  const int kg  = blockIdx.x & 3;  // k-group: chunks {kg + 4j}
  const int blockTok = tr * 128;

  float4 accL[8], accH[8];
#pragma unroll
  for (int j = 0; j < 8; ++j) {
    accL[j] = make_float4(0.f, 0.f, 0.f, 0.f);
    accH[j] = make_float4(0.f, 0.f, 0.f, 0.f);
  }

  auto a_src = [&](int g, int row) -> const float* {
    const float* base; int stride;
    if (g < 16)      { base = mh + g * 64;        stride = 1024; }
    else if (g < 20) { base = dt + (g - 16) * 64; stride = 256; }
    else if (g < 24) { base = dd + (g - 20) * 64; stride = 256; }
    else             { base = (g < 26) ? rg + (g - 24) * 64
                                       : de + (g - 26) * 64;
                       stride = 128; }
    return base + (size_t)(blockTok + row) * stride;
  };

  // A: 2048 f4 slots, 4 DMA/thread, linear LDS dest, source col pre-XOR'd
  auto stageA = [&](int g, float* Ab) {
#pragma unroll
    for (int i = 0; i < 4; ++i) {
      const int slot = i * 512 + tid;
      const int r    = slot >> 4;                 // token row 0..127
      const int c4   = (slot & 15) ^ (r & 15);    // swizzled source col
      dma16(a_src(g, r) + c4 * 4, Ab + slot * 4);
    }
  };
  // W: 1 f4/thread into regs (global), later ds_write to sW
  auto wglb = [&](int g) -> float4 {
    const int r  = tid >> 3;               // k-row 0..63
    const int c4 = tid & 7;                // 8 f4 per row (32 e)
    const int kb = g * 64 + ((g >= 16) ? 32 : 0) + r;  // skip city rows
    const float* p = (c4 < 4) ? (w_route + kb * 16 + c4 * 4)
                              : (w_noise + kb * 16 + (c4 - 4) * 4);
    return *(const float4*)p;
  };

  float* A0 = smem;
  float* A1 = smem + 8192;
  float4 WRn;

  // prologue: chunk 0 of this k-group
  {
    const int g0 = kg;
    WRn = wglb(g0);
    stageA(g0, A0);
    asm volatile("s_waitcnt vmcnt(0)" ::: "memory");
    __syncthreads();
    *(float4*)&sW[tid * 4] = WRn;
    __syncthreads();
  }

  const int c4x0 = (((w << 1) | 0) ^ tg) << 2;   // swizzled A read cols
  const int c4x1 = (((w << 1) | 1) ^ tg) << 2;
  const int k0 = w * 8;

  for (int j = 0; j < NCHUNK; ++j) {
    const float* A = (j & 1) ? A1 : A0;

    if (j + 1 < NCHUNK) {            // into buffer freed by barrier (j-1)
      stageA(kg + 4 * (j + 1), (j & 1) ? A0 : A1);
      WRn = wglb(kg + 4 * (j + 1));
    }

#pragma unroll
    for (int q = 0; q < 2; ++q) {
      const int cofs = q ? c4x1 : c4x0;
      float4 a[8];
#pragma unroll
      for (int jj = 0; jj < 8; ++jj)
        a[jj] = *(const float4*)&A[(tg + 16 * jj) * 64 + cofs];
#pragma unroll
      for (int kk = 0; kk < 4; ++kk) {
        const int krow = k0 + q * 4 + kk;
        float4 wv0 = *(const float4*)&sW[krow * 32 + eg * 8];      // bcast
        float4 wv1 = *(const float4*)&sW[krow * 32 + eg * 8 + 4];  // bcast
#pragma unroll
        for (int jj = 0; jj < 8; ++jj) {
          const float s = get_comp(a[jj], kk);
          accL[jj].x = fmaf(s, wv0.x, accL[jj].x);
          accL[jj].y = fmaf(s, wv0.y, accL[jj].y);
          accL[jj].z = fmaf(s, wv0.z, accL[jj].z);
          accL[jj].w = fmaf(s, wv0.w, accL[jj].w);
          accH[jj].x = fmaf(s, wv1.x, accH[jj].x);
          accH[jj].y = fmaf(s, wv1.y, accH[jj].y);
          accH[jj].z = fmaf(s, wv1.z, accH[jj].z);
          accH[jj].w = fmaf(s, wv1.w, accH[jj].w);
        }
      }
    }

    if (j + 1 < NCHUNK) {
      // A(j+1)/W(j+1) were issued a full compute-phase ago: not a convoy
      asm volatile("s_waitcnt vmcnt(0)" ::: "memory");
      __syncthreads();                 // everyone done reading sW + A(j)
      *(float4*)&sW[tid * 4] = WRn;    // publish W(j+1)
      __syncthreads();
    }
  }
  __syncthreads();   // all compute done; A-ring dead -> sS overlay

  // ---- 8-way split-K (waves) reduction into sS[128][36] ----
  for (int r = 0; r < 8; ++r) {
    if (w == r) {
#pragma unroll
      for (int jj = 0; jj < 8; ++jj) {
        float* p = &sS[(tg + 16 * jj) * SS + eg * 8];
        if (r == 0) {
          *(float4*)(p)     = accL[jj];
          *(float4*)(p + 4) = accH[jj];
        } else {
          float4 x0 = *(float4*)(p), x1 = *(float4*)(p + 4);
          x0.x += accL[jj].x; x0.y += accL[jj].y; x0.z += accL[jj].z; x0.w += accL[jj].w;
          x1.x += accH[jj].x; x1.y += accH[jj].y; x1.z += accH[jj].z; x1.w += accH[jj].w;
          *(float4*)(p)     = x0;
          *(float4*)(p + 4) = x1;
        }
      }
    }
    __syncthreads();
  }

  // ---- write partials: ws[bid][tok][32] contiguous ----
  float* wsp = ws + (size_t)blockIdx.x * (128 * 32);
#pragma unroll
  for (int i = 0; i < 2; ++i) {
    const int slot = i * 512 + tid;          // f4-slot 0..1023
    const int tok  = slot >> 3;
    const int e4   = slot & 7;
    *(float4*)(wsp + slot * 4) = *(const float4*)&sS[tok * SS + e4 * 4];
  }
}

// ---------------- kernel 2: combine partials + epilogue ----------------
__global__ __launch_bounds__(128) void router_epilogue(
    const float* __restrict__ ws, const float* __restrict__ cemb_all,
    const float* __restrict__ w_route, const float* __restrict__ b_route,
    const float* __restrict__ w_noise, const float* __restrict__ b_noise,
    const float* __restrict__ eps, const int* __restrict__ city_index,
    float* __restrict__ out) {
  __shared__ float city_l[32];
  const int tid = threadIdx.x;
  if (tid < 32) {
    const int e = tid & 15;
    const float* wsrc = (tid < 16) ? w_route : w_noise;
    const float* bsrc = (tid < 16) ? b_route : b_noise;
    const float* ce = cemb_all + city_index[0] * 32;
    float sacc = bsrc[e];
#pragma unroll
    for (int j = 0; j < 32; ++j)
      sacc = fmaf(ce[j], wsrc[(1024 + j) * 16 + e], sacc);
    city_l[tid] = sacc;
  }
  __syncthreads();

  const int t  = blockIdx.x * 128 + tid;   // token 0..32767
  const int tr = t >> 7, tl = t & 127;

  float l[32];
#pragma unroll
  for (int e = 0; e < 32; ++e) l[e] = city_l[e];
#pragma unroll
  for (int kg = 0; kg < 4; ++kg) {
    const float* p = ws + (((size_t)(tr * 4 + kg) * 128) + tl) * 32;
#pragma unroll
    for (int e4 = 0; e4 < 8; ++e4) {
      float4 v = *(const float4*)(p + e4 * 4);
      l[e4 * 4 + 0] += v.x; l[e4 * 4 + 1] += v.y;
      l[e4 * 4 + 2] += v.z; l[e4 * 4 + 3] += v.w;
    }
  }

  const float* ep = eps + (size_t)t * 16;
  float n[16];
#pragma unroll
  for (int e = 0; e < 16; ++e)
    n[e] = fmaf(ep[e], softplus_f(l[16 + e]), l[e]);

  // top-2, lowest-index tie-break (matches lax.top_k)
  float m1 = -INFINITY; int i1 = 0;
#pragma unroll
  for (int e = 0; e < 16; ++e)
    if (n[e] > m1) { m1 = n[e]; i1 = e; }
  float m2 = -INFINITY; int i2 = 0;
#pragma unroll
  for (int e = 0; e < 16; ++e)
    if (e != i1 && n[e] > m2) { m2 = n[e]; i2 = e; }

  float ex[16], Z = 0.f;
#pragma unroll
  for (int e = 0; e < 16; ++e) { ex[e] = expf(n[e] - m1); Z += ex[e]; }
  const float invZ  = 1.0f / Z;
  const float invZ2 = 1.0f / (1.0f + expf(m2 - m1));  // ex[i1]=1

  float r[16], g1[16];
#pragma unroll
  for (int e = 0; e < 16; ++e) {
    r[e]  = (e == i1 || e == i2) ? ex[e] * invZ2 : 0.0f;
    g1[e] = ex[e] * invZ;
  }

  float* ro = out + (size_t)t * 16;
#pragma unroll
  for (int e4 = 0; e4 < 4; ++e4)
    *(float4*)(ro + e4 * 4) = make_float4(r[e4*4], r[e4*4+1], r[e4*4+2], r[e4*4+3]);

  out[I_OFF + (size_t)t * 2 + 0] = (float)i1;
  out[I_OFF + (size_t)t * 2 + 1] = (float)i2;

  float* go = out + G_OFF + (size_t)t * 16;
#pragma unroll
  for (int e4 = 0; e4 < 4; ++e4)
    *(float4*)(go + e4 * 4) = make_float4(g1[e4*4], g1[e4*4+1], g1[e4*4+2], g1[e4*4+3]);
}

extern "C" void kernel_launch(void* const* d_in, const int* in_sizes, int n_in,
                              void* d_out, int out_size, void* d_ws, size_t ws_size,
                              hipStream_t stream) {
  const float* mh = (const float*)d_in[0];   // [8,4096,1024]
  const float* dt = (const float*)d_in[1];   // [8,4096,256]
  const float* dd = (const float*)d_in[2];   // [8,4096,256]
  const float* rg = (const float*)d_in[3];   // [8,4096,128]
  const float* de = (const float*)d_in[4];   // [8,4096,128]
  const float* ce = (const float*)d_in[5];   // [4,32]
  const float* wr = (const float*)d_in[6];   // [1824,16]
  const float* br = (const float*)d_in[7];   // [16]
  const float* wn = (const float*)d_in[8];   // [1824,16]
  const float* bn = (const float*)d_in[9];   // [16]
  const float* ep = (const float*)d_in[10];  // [8,4096,16]
  const int*   ci = (const int*)d_in[11];    // scalar
  float* out = (float*)d_out;
  float* ws  = (float*)d_ws;                 // 1024*128*32*4 = 16.8 MB

  router_gemm<<<1024, 512, 0, stream>>>(mh, dt, dd, rg, de, wr, wn, ws);
  router_epilogue<<<256, 128, 0, stream>>>(ws, ce, wr, br, wn, bn, ep, ci, out);
}